// Round 15
// baseline (145.114 us; speedup 1.0000x reference)
//
#include <hip/hip_runtime.h>
#include <math.h>

#define DD 4096
#define EE 64
#define TAU 1e-4f
#define NEG_SENTINEL -1.0e30f
#define MAXFIX 4096

typedef __attribute__((ext_vector_type(8))) short short8v;
typedef __attribute__((ext_vector_type(4))) float f32x4;

union BF8 { uint4 u; short8v s; };

__device__ __forceinline__ unsigned asu(float f) {
  union { float f; unsigned u; } v; v.f = f; return v.u;
}
__device__ __forceinline__ float asf(unsigned u) {
  union { unsigned u; float f; } v; v.u = u; return v.f;
}
__device__ __forceinline__ unsigned rne_hi(float x) {  // bf16 bits<<16
  unsigned u = asu(x);
  return (u + 0x7fffu + ((u >> 16) & 1u)) & 0xffff0000u;
}
// Split 8 f32 into hi/lo bf16 (RNE both): x = hi + lo + O(2^-17 |x|).
__device__ __forceinline__ void split8(const float x[8], uint4& hi, uint4& lo) {
  unsigned h[8], l[8];
#pragma unroll
  for (int j = 0; j < 8; j++) {
    h[j] = rne_hi(x[j]);
    l[j] = rne_hi(x[j] - asf(h[j]));
  }
  hi = make_uint4((h[0] >> 16) | h[1], (h[2] >> 16) | h[3],
                  (h[4] >> 16) | h[5], (h[6] >> 16) | h[7]);
  lo = make_uint4((l[0] >> 16) | l[1], (l[2] >> 16) | l[3],
                  (l[4] >> 16) | l[5], (l[6] >> 16) | l[7]);
}
// global -> LDS direct copy, 16B/lane; LDS dest wave-uniform (HW adds l*16).
__device__ __forceinline__ void gload16(const void* g, void* l) {
  __builtin_amdgcn_global_load_lds(
      (const __attribute__((address_space(1))) uint32_t*)(uintptr_t)g,
      (__attribute__((address_space(3))) uint32_t*)(uint32_t)(uintptr_t)l, 16,
      0, 0);
}

// ---------------------------------------------------------------------------
// Kernel 0: pre-split gate_w into bf16 hi/lo, laid out for DIRECT per-wave
// register reads: bglob[slice(1024k)][step(32k)][plane hi|lo][nt][fg][fr]
// -> each B-fragment load is one contiguous 1KB wave window (lane = fg*16+fr
// reads expert nt*16+fr, k-octet fg). Slice stride 256KB.
// ---------------------------------------------------------------------------
__global__ __launch_bounds__(256) void presplit_b(const float* __restrict__ gw,
                                                  char* __restrict__ bglob) {
  const int t = blockIdx.x * 256 + threadIdx.x;  // 64 e x 512 octets
  const int e = t >> 9;
  const int o = t & 511;
  const int slice = o >> 7;   // 128 octets per 1024-k slice
  const int ow = o & 127;
  const int step = ow >> 2;   // 32 steps x 4 octets
  const int o2 = ow & 3;      // k-octet within step = fg
  const float* src = gw + e * DD + o * 8;
  float4 v0 = *(const float4*)src;
  float4 v1 = *(const float4*)(src + 4);
  float x[8] = {v0.x, v0.y, v0.z, v0.w, v1.x, v1.y, v1.z, v1.w};
  uint4 hi, lo;
  split8(x, hi, lo);
  char* dst = bglob + (size_t)slice * 262144 + step * 8192 + (e >> 4) * 1024 +
              o2 * 256 + (e & 15) * 16;
  *(uint4*)dst = hi;
  *(uint4*)(dst + 4096) = lo;
}

// ---------------------------------------------------------------------------
// Kernel 1 (R15): BARRIER-FREE wave-private pipeline.
// Block = 64 rows, 4 waves; wave = 16 rows (mt=1) x 64 e (nt=4), stages ITS
// OWN A rows into wave-private LDS (2KB/buf) -> no __syncthreads anywhere.
// A: gload_lds (R12-proven source swizzle slot^(row&7)), dbuf 2x8KB/block.
// B: direct 1KB-contiguous register loads from pre-split bglob (L2-hot),
//    reg double-buffer.
// Per step: issue A(t+1)[2 gload] + B(t+1)[8 uint4] -> s_waitcnt vmcnt(10)
// (drains A(t)+B(t) exactly; t+1 stays in flight) -> 2 ds_read + split8 +
// 12 MFMA. grid (nrows/64, 4) = 1024 = 4 blocks/CU exactly resident ->
// 4 waves/SIMD with VGPR<=128.
// ---------------------------------------------------------------------------
__global__ __launch_bounds__(256, 4) void gemm_mfma(
    const float* __restrict__ hidden, const char* __restrict__ bglob,
    float* __restrict__ part, int nrows) {
  __shared__ __align__(16) char smem[16384];  // 2 bufs x (4 waves x 2KB)

  const int lane = threadIdx.x & 63;
  const int wv = threadIdx.x >> 6;
  const int fr = lane & 15;
  const int fg = lane >> 4;  // 0..3
  const int m0 = blockIdx.x * 64;
  const int slice = blockIdx.y;  // ksplit = 4, kslice = 1024
  const int k0 = slice * 1024;

  // A sources (R12-proven): wave wv stages rows 16wv..+15; instr i covers
  // rows 8i..8i+7. lane l -> rloc = 8i+(l>>3), source slot (l&7)^(rloc&7).
  const float* srcA[2];
#pragma unroll
  for (int i = 0; i < 2; i++) {
    const int rloc = 8 * i + (lane >> 3);
    const int s = (lane & 7) ^ (rloc & 7);
    srcA[i] = hidden + (size_t)(m0 + 16 * wv + rloc) * DD + k0 + s * 4;
  }
  const char* pB = bglob + (size_t)slice * 262144 + lane * 16;

  auto stageA = [&](int t) {
    char* ad = smem + (t & 1) * 8192 + wv * 2048;
    gload16(srcA[0] + t * 32, ad);
    gload16(srcA[1] + t * 32, ad + 1024);
  };

  uint4 bc[8], bn[8];
#define LOADB(DST, T)                                                        \
  _Pragma("unroll") for (int i = 0; i < 8; i++) {                            \
    DST[i] = *(const uint4*)(pB + (T) * 8192 + (i >> 2) * 4096 + (i & 3) * 1024); \
  }

  f32x4 zero4 = {0.f, 0.f, 0.f, 0.f};
  f32x4 acc[4];
#pragma unroll
  for (int nt = 0; nt < 4; nt++) acc[nt] = zero4;

  const int abase = wv * 2048 + fr * 128;

  // prologue: A(0)+B(0) in flight (10 ops)
  stageA(0);
  LOADB(bc, 0)

  for (int t = 0; t < 32; t++) {
    if (t + 1 < 32) {
      stageA(t + 1);
      LOADB(bn, t + 1)
      // oldest 10 = A(t)+B(t) done; A(t+1)+B(t+1) stay in flight
      asm volatile("s_waitcnt vmcnt(10)" ::: "memory");
    } else {
      asm volatile("s_waitcnt vmcnt(0)" ::: "memory");
    }

    const char* Ab = smem + (t & 1) * 8192;
    float4 a0 = *(const float4*)(Ab + abase + (((2 * fg + 0) ^ (fr & 7)) << 4));
    float4 a1 = *(const float4*)(Ab + abase + (((2 * fg + 1) ^ (fr & 7)) << 4));
    float xa[8] = {a0.x, a0.y, a0.z, a0.w, a1.x, a1.y, a1.z, a1.w};
    BF8 ah, al;
    split8(xa, ah.u, al.u);
    BF8 bh[4], bl[4];
#pragma unroll
    for (int nt = 0; nt < 4; nt++) {
      bh[nt].u = bc[nt];
      bl[nt].u = bc[4 + nt];
    }
    // 12 MFMAs, pass-outer (per-acc order hh->hl->lh, deterministic)
#pragma unroll
    for (int nt = 0; nt < 4; nt++)
      acc[nt] = __builtin_amdgcn_mfma_f32_16x16x32_bf16(ah.s, bh[nt].s,
                                                        acc[nt], 0, 0, 0);
#pragma unroll
    for (int nt = 0; nt < 4; nt++)
      acc[nt] = __builtin_amdgcn_mfma_f32_16x16x32_bf16(ah.s, bl[nt].s,
                                                        acc[nt], 0, 0, 0);
#pragma unroll
    for (int nt = 0; nt < 4; nt++)
      acc[nt] = __builtin_amdgcn_mfma_f32_16x16x32_bf16(al.s, bh[nt].s,
                                                        acc[nt], 0, 0, 0);
    // roll B regs
#pragma unroll
    for (int i = 0; i < 8; i++) bc[i] = bn[i];
  }
#undef LOADB

  // partial logits part[slice][row][e]; C/D row=fg*4+j, col=fr
  float* dst = part + (size_t)slice * nrows * EE;
#pragma unroll
  for (int j = 0; j < 4; j++) {
    const int r = m0 + 16 * wv + fg * 4 + j;
#pragma unroll
    for (int nt = 0; nt < 4; nt++)
      dst[(size_t)r * EE + nt * 16 + fr] = acc[nt][j];
  }
}

// ---------------------------------------------------------------------------
// Kernel 2: reduce partials, sqrt(softplus), top-8 (lax.top_k tie-break),
// renormalize, scatter. Flags rows with margin < TAU for exact recompute.
// ---------------------------------------------------------------------------
__global__ __launch_bounds__(256) void topk_kernel(
    const float* __restrict__ part, const float* __restrict__ bias,
    float* __restrict__ out, int nrows, int ksplit, int* __restrict__ counter,
    int* __restrict__ list) {
  const int lane = threadIdx.x & 63;
  const int row = blockIdx.x * 4 + (threadIdx.x >> 6);

  float logit = 0.0f;
  for (int s = 0; s < ksplit; s++)
    logit += part[(size_t)s * nrows * EE + (size_t)row * EE + lane];

  float sp = (logit > 0.0f) ? (logit + log1pf(expf(-logit)))
                            : log1pf(expf(logit));
  float score = sqrtf(sp);
  float sel = score + bias[lane];

  float denom = 0.0f, v8 = 0.0f;
  bool chosen = false;
#pragma unroll
  for (int t = 0; t < 8; t++) {
    float v = sel;
    int idx = lane;
#pragma unroll
    for (int m = 1; m < 64; m <<= 1) {
      float ov = __shfl_xor(v, m, 64);
      int oi = __shfl_xor(idx, m, 64);
      if (ov > v || (ov == v && oi < idx)) { v = ov; idx = oi; }
    }
    float wscore = __shfl(score, idx, 64);
    denom += wscore;
    v8 = v;
    if (lane == idx) { chosen = true; sel = NEG_SENTINEL; }
  }
  float v9 = sel;
#pragma unroll
  for (int m = 1; m < 64; m <<= 1) v9 = fmaxf(v9, __shfl_xor(v9, m, 64));
  if (lane == 0 && (v8 - v9) < TAU) {
    int ix = atomicAdd(counter, 1);
    if (ix < MAXFIX) list[ix] = row;
  }

  denom = fmaxf(denom, 1e-12f);
  out[(size_t)row * EE + lane] = chosen ? (score / denom) : 0.0f;
  out[(size_t)nrows * EE + (size_t)row * EE + lane] = chosen ? 1.0f : 0.0f;
}

// ---------------------------------------------------------------------------
// Kernel 3a: exact-f32 partial dots for flagged rows, k-split 16 ways.
// ---------------------------------------------------------------------------
__global__ __launch_bounds__(256) void fixup_partial(
    const float* __restrict__ hidden, const float* __restrict__ gate_w,
    const int* __restrict__ counter, const int* __restrict__ list,
    float* __restrict__ part2) {
  __shared__ float red[EE][4];
  int cnt = *counter;
  if (cnt > MAXFIX) cnt = MAXFIX;
  const int total = cnt * 16;
  const int e = threadIdx.x & 63;
  const int q = threadIdx.x >> 6;
  for (int w = blockIdx.x; w < total; w += gridDim.x) {
    const int i = w >> 4;
    const int c = w & 15;
    const int row = list[i];
    const int kb = c * 256 + q * 64;
    const float* hp = hidden + (size_t)row * DD + kb;
    const float* wp = gate_w + (size_t)e * DD + kb;
    float s = 0.f;
#pragma unroll
    for (int k = 0; k < 64; k += 4) {
      float4 aa = *(const float4*)(hp + k);
      float4 bb = *(const float4*)(wp + k);
      s = fmaf(aa.w, bb.w, fmaf(aa.z, bb.z, fmaf(aa.y, bb.y, fmaf(aa.x, bb.x, s))));
    }
    red[e][q] = s;
    __syncthreads();
    if (threadIdx.x < EE)
      part2[(size_t)i * 1024 + threadIdx.x * 16 + c] =
          (red[threadIdx.x][0] + red[threadIdx.x][1]) +
          (red[threadIdx.x][2] + red[threadIdx.x][3]);
    __syncthreads();
  }
}

// ---------------------------------------------------------------------------
// Kernel 3b: sum the 16 chunks in fixed order, redo top-8 exactly, rewrite.
// ---------------------------------------------------------------------------
__global__ __launch_bounds__(256) void fixup_apply(
    const float* __restrict__ part2, const float* __restrict__ bias,
    const int* __restrict__ counter, const int* __restrict__ list,
    float* __restrict__ out, int nrows) {
  int cnt = *counter;
  if (cnt > MAXFIX) cnt = MAXFIX;
  const int lane = threadIdx.x & 63;
  const int wv = threadIdx.x >> 6;
  for (int i0 = blockIdx.x * 4; i0 < cnt; i0 += gridDim.x * 4) {
    const int i = i0 + wv;
    if (i >= cnt) continue;
    const int row = list[i];
    const float* pp = part2 + (size_t)i * 1024 + lane * 16;
    float logit = 0.f;
#pragma unroll
    for (int c = 0; c < 16; c++) logit += pp[c];
    float sp = (logit > 0.0f) ? (logit + log1pf(expf(-logit)))
                              : log1pf(expf(logit));
    float score = sqrtf(sp);
    float sel = score + bias[lane];
    float denom = 0.0f;
    bool chosen = false;
#pragma unroll
    for (int k = 0; k < 8; k++) {
      float v = sel;
      int idx = lane;
#pragma unroll
      for (int m = 1; m < 64; m <<= 1) {
        float ov = __shfl_xor(v, m, 64);
        int oi = __shfl_xor(idx, m, 64);
        if (ov > v || (ov == v && oi < idx)) { v = ov; idx = oi; }
      }
      float wscore = __shfl(score, idx, 64);
      denom += wscore;
      if (lane == idx) { chosen = true; sel = NEG_SENTINEL; }
    }
    denom = fmaxf(denom, 1e-12f);
    out[(size_t)row * EE + lane] = chosen ? (score / denom) : 0.0f;
    out[(size_t)nrows * EE + (size_t)row * EE + lane] = chosen ? 1.0f : 0.0f;
  }
}

// ---------------------------------------------------------------------------
extern "C" void kernel_launch(void* const* d_in, const int* in_sizes, int n_in,
                              void* d_out, int out_size, void* d_ws,
                              size_t ws_size, hipStream_t stream) {
  const float* hidden = (const float*)d_in[0];
  const float* gate_w = (const float*)d_in[1];
  const float* bias = (const float*)d_in[2];
  float* out = (float*)d_out;
  char* ws = (char*)d_ws;

  const int nrows = in_sizes[0] / DD;  // 16384

  // ws: bglob @0 (1MB) | part @2MB (16MB) | part2 @20MB (16MB) | tail ctr
  char* bglob = ws;
  float* part = (float*)(ws + (size_t)2 * 1024 * 1024);
  float* part2 = (float*)(ws + (size_t)20 * 1024 * 1024);
  size_t tail = (ws_size - 65536) & ~(size_t)255;
  int* counter = (int*)(ws + tail);
  int* list = counter + 1;

  hipMemsetAsync(counter, 0, sizeof(int), stream);
  presplit_b<<<dim3(128), dim3(256), 0, stream>>>(gate_w, bglob);
  gemm_mfma<<<dim3(nrows / 64, 4), dim3(256), 0, stream>>>(hidden, bglob, part,
                                                           nrows);
  topk_kernel<<<dim3(nrows / 4), dim3(256), 0, stream>>>(part, bias, out,
                                                         nrows, 4, counter,
                                                         list);
  fixup_partial<<<dim3(2048), dim3(256), 0, stream>>>(hidden, gate_w, counter,
                                                      list, part2);
  fixup_apply<<<dim3(512), dim3(256), 0, stream>>>(part2, bias, counter, list,
                                                   out, nrows);
}